// Round 16
// baseline (179.200 us; speedup 1.0000x reference)
//
#include <hip/hip_runtime.h>
#include <math.h>

#define NQ 6
#define NL 3

typedef float v2f __attribute__((ext_vector_type(2)));

// ---------- CNOT-ring permutation (bench-validated rounds 2-15) ----------
constexpr int cnot_map(int k, int ctrl, int tgt) {
    const int cb = 1 << (5 - ctrl), tb = 1 << (5 - tgt);
    return (k & cb) ? (k ^ tb) : k;
}
constexpr int ring_map(int k) {
    k = cnot_map(k, 5, 0);
    k = cnot_map(k, 4, 5);
    k = cnot_map(k, 3, 4);
    k = cnot_map(k, 2, 3);
    k = cnot_map(k, 1, 2);
    k = cnot_map(k, 0, 1);
    return k;
}
constexpr int ringN(int k, int n) {
    for (int i = 0; i < n; i++) k = ring_map(k);
    return k;
}
constexpr int inv_ringN(int p, int n) {
    for (int k = 0; k < 64; k++) if (ringN(k, n) == p) return k;
    return -1;
}
// Gate on logical qubit q with l rings skipped: physical pair mask Δ
constexpr int DELTA(int l, int q) { return ringN(1 << (5 - q), l); }
// Side mask σ: parity(σ & p) == logical bit (5-q) of physical p
constexpr int SIGMA(int l, int q) {
    int m = 0;
    for (int i = 0; i < 6; i++)
        if ((inv_ringN(1 << i, l) >> (5 - q)) & 1) m |= 1 << i;
    return m;
}
// Exhaustive verification vs validated ring_map: pairing linearity, side
// indicator for every physical index, and σ·Δ = 1 (pair straddles the gate).
constexpr bool check_conj() {
    int fwd[4][64] = {}, inv[4][64] = {};
    for (int k = 0; k < 64; k++) fwd[0][k] = k;
    for (int l = 1; l <= 3; l++)
        for (int k = 0; k < 64; k++) fwd[l][k] = ring_map(fwd[l - 1][k]);
    for (int l = 0; l <= 3; l++)
        for (int k = 0; k < 64; k++) inv[l][fwd[l][k]] = k;
    for (int l = 0; l <= 3; l++)
        for (int q = 0; q < 6; q++) {
            const int sg = SIGMA(l, q), dl = DELTA(l, q);
            for (int p = 0; p < 64; p++)
                if ((__builtin_popcount(sg & p) & 1) != ((inv[l][p] >> (5 - q)) & 1))
                    return false;
            if ((__builtin_popcount(sg & dl) & 1) != 1) return false;
            for (int k = 0; k < 64; k++)
                if (fwd[l][k ^ (1 << (5 - q))] != (fwd[l][k] ^ dl)) return false;
        }
    return true;
}
static_assert(check_conj(), "ring-conjugation masks mismatch vs validated ring_map");

// ---- prep kernel: M = RZ(a2)@RY(a1)@RZ(a0), SU(2) form (m00, m01) ----
__global__ void gate_prep(const float* __restrict__ w, float4* __restrict__ M) {
    const int g = threadIdx.x;
    if (g >= NL * NQ) return;
    const float a0 = w[g * 3 + 0], a1 = w[g * 3 + 1], a2 = w[g * 3 + 2];
    const float ch = cosf(0.5f * a1), sh = sinf(0.5f * a1);
    const float cp = cosf(0.5f * (a0 + a2)), sp = sinf(0.5f * (a0 + a2));
    const float cm = cosf(0.5f * (a0 - a2)), sm = sinf(0.5f * (a0 - a2));
    M[g] = make_float4(ch * cp, -ch * sp, -sh * cm, -sh * sm);
}

// G = M @ RY(c,s): g00 = m00*c + m01*s ; g01 = -m00*s + m01*c  (SU(2))
#define GCOEF(mq, c, s, g00r, g00i, g01r, g01i)                         \
    const float g00r = (mq).x * (c) + (mq).z * (s);                     \
    const float g00i = (mq).y * (c) + (mq).w * (s);                     \
    const float g01r = (mq).z * (c) - (mq).x * (s);                     \
    const float g01i = (mq).w * (c) - (mq).y * (s);

// Element coefficients by side s: A_0=g00, A_1=conj g00 (same real part);
// B_0=g01, B_1=-conj g01 (same imag part). Per-element:
//   new_r = e_r*g00r - e_i*KAi + p_r*KBr - p_i*g01i
//   new_i = e_i*g00r + e_r*KAi + p_i*KBr + p_r*g01i
// KAi(side) = side ? -g00i : g00i ; KBr(side) = side ? -g01r : g01r.
// Layout: physical index p = 2m + c (vector m = bits5..1, comp c = bit0).
// Pairing: m <-> m ^ vm; canonical selector = one bit of vm (round-14 fix).
#define APPLY_GATE(L, Q) do {                                               \
    constexpr int dlt = DELTA(L, Q);                                        \
    constexpr int sgm = SIGMA(L, Q);                                        \
    constexpr int vm  = dlt >> 1;                                           \
    constexpr int cf  = dlt & 1;                                            \
    constexpr int tt  = sgm & 1;                                            \
    constexpr int cvm = vm & (-vm);   /* single canonical bit of vm */      \
    const float4 mq = M[(L) * NQ + (Q)];                                    \
    GCOEF(mq, C[Q], S[Q], g00r, g00i, g01r, g01i)                           \
    if constexpr (cf == 0) {                                                \
        /* partner keeps comp */                                            \
        _Pragma("unroll")                                                   \
        for (int m = 0; m < 32; m++) if (!(m & cvm)) {                      \
            const int m2 = m ^ vm;                                          \
            const int s0 = __builtin_popcount(sgm & (2 * m)) & 1;           \
            const v2f KAi = (v2f){ s0 ? -g00i : g00i, (s0^tt) ? -g00i : g00i }; \
            const v2f KBr = (v2f){ s0 ? -g01r : g01r, (s0^tt) ? -g01r : g01r }; \
            const v2f R0 = Rr[m], I0 = Ri[m], R1 = Rr[m2], I1 = Ri[m2];     \
            Rr[m]  = R0 * g00r - I0 * KAi + R1 * KBr - I1 * g01i;           \
            Ri[m]  = I0 * g00r + R0 * KAi + I1 * KBr + R1 * g01i;           \
            Rr[m2] = R1 * g00r + I1 * KAi - R0 * KBr - I0 * g01i;           \
            Ri[m2] = I1 * g00r - R1 * KAi - I0 * KBr + R0 * g01i;           \
        }                                                                   \
    } else if constexpr (vm == 0) {                                         \
        /* pure comp-flip: partner = own .yx */                             \
        _Pragma("unroll")                                                   \
        for (int m = 0; m < 32; m++) {                                      \
            const int s0 = __builtin_popcount(sgm & (2 * m)) & 1;           \
            const v2f KAi = (v2f){ s0 ? -g00i : g00i, (s0^tt) ? -g00i : g00i }; \
            const v2f KBr = (v2f){ s0 ? -g01r : g01r, (s0^tt) ? -g01r : g01r }; \
            const v2f R0 = Rr[m], I0 = Ri[m];                               \
            const v2f R0s = (v2f){R0.y, R0.x}, I0s = (v2f){I0.y, I0.x};     \
            Rr[m] = R0 * g00r - I0 * KAi + R0s * KBr - I0s * g01i;          \
            Ri[m] = I0 * g00r + R0 * KAi + I0s * KBr + R0s * g01i;          \
        }                                                                   \
    } else {                                                                \
        /* cross-vector + comp-flip: partner = other vector .yx */          \
        _Pragma("unroll")                                                   \
        for (int m = 0; m < 32; m++) if (!(m & cvm)) {                      \
            const int m2 = m ^ vm;                                          \
            const int s0 = __builtin_popcount(sgm & (2 * m)) & 1;           \
            const v2f KAi  = (v2f){ s0 ? -g00i : g00i, (s0^tt) ? -g00i : g00i };    \
            const v2f KBr  = (v2f){ s0 ? -g01r : g01r, (s0^tt) ? -g01r : g01r };    \
            const v2f KAi2 = (v2f){ (s0^1^tt) ? -g00i : g00i, (s0^1) ? -g00i : g00i }; \
            const v2f KBr2 = (v2f){ (s0^1^tt) ? -g01r : g01r, (s0^1) ? -g01r : g01r }; \
            const v2f R0 = Rr[m], I0 = Ri[m], R1 = Rr[m2], I1 = Ri[m2];     \
            const v2f R1s = (v2f){R1.y, R1.x}, I1s = (v2f){I1.y, I1.x};     \
            const v2f R0s = (v2f){R0.y, R0.x}, I0s = (v2f){I0.y, I0.x};     \
            Rr[m]  = R0 * g00r - I0 * KAi  + R1s * KBr  - I1s * g01i;       \
            Ri[m]  = I0 * g00r + R0 * KAi  + I1s * KBr  + R1s * g01i;       \
            Rr[m2] = R1 * g00r - I1 * KAi2 + R0s * KBr2 - I0s * g01i;       \
            Ri[m2] = I1 * g00r + R1 * KAi2 + I0s * KBr2 + R0s * g01i;       \
        }                                                                   \
    }                                                                       \
} while (0)

// __launch_bounds__(256, 4): grid supplies exactly 4 waves/SIMD; 4 waves fit
// up to 128 VGPR (512/SIMD pool). Round-15's implicit budget gave VGPR=104 <
// the 128-VGPR live state => allocator remat/shuffle fat. Ask for the full 128.
__global__ __launch_bounds__(256, 4)
void qsim_kernel(const float* __restrict__ x, const float4* __restrict__ M,
                 float* __restrict__ out, int B) {
    const int b = blockIdx.x * blockDim.x + threadIdx.x;
    if (b >= B) return;

    const float2* x2 = (const float2*)x;
    const float2 v0 = x2[b * 3 + 0];
    const float2 v1 = x2[b * 3 + 1];
    const float2 v2 = x2[b * 3 + 2];
    const float xi[NQ] = {v0.x, v0.y, v1.x, v1.y, v2.x, v2.y};

    // phi = (pi/2)*tanh(x); v_sin/v_cos take REVOLUTIONS: |t/4| <= 0.25
    float C[NQ], S[NQ];
#pragma unroll
    for (int i = 0; i < NQ; i++) {
        const float e = __builtin_amdgcn_exp2f(2.885390081777927f * xi[i]); // e^{2x}
        const float t = 1.0f - 2.0f * __builtin_amdgcn_rcpf(e + 1.0f);      // tanh(x)
        S[i] = __builtin_amdgcn_sinf(0.25f * t);
        C[i] = __builtin_amdgcn_cosf(0.25f * t);
    }

    // Full 64-amp state per thread, packed: Rr[m]/Ri[m] comps = amps 2m, 2m+1
    v2f Rr[32], Ri[32];

    // ---- layer 0 on |0>: product-state cascade, scalar until q5 ----
    float ar0[32], ai0[32];
    {
        const float4 m0 = M[0];
        GCOEF(m0, C[0], S[0], g00r, g00i, g01r, g01i)
        ar0[0]  = g00r;  ai0[0]  = g00i;    // amp 0  (m=0)
        ar0[16] = -g01r; ai0[16] = g01i;    // amp 32 (m=16): -conj(g01)
    }
#pragma unroll
    for (int q = 1; q < 5; q++) {
        const float4 mq = M[q];
        GCOEF(mq, C[q], S[q], g00r, g00i, g01r, g01i)
        const float Ar = g00r, Ai = g00i;     // bit=0 factor
        const float Br = -g01r, Bi = g01i;    // bit=1 factor (-conj g01)
        const int mb = 16 >> q;
#pragma unroll
        for (int m = 0; m < 32; m++) {
            if ((m & ((32 >> q) - 1)) == 0) {  // occupied set
                const float pr = ar0[m], pi = ai0[m];
                ar0[m | mb] = pr * Br - pi * Bi;
                ai0[m | mb] = pr * Bi + pi * Br;
                ar0[m] = pr * Ar - pi * Ai;
                ai0[m] = pr * Ai + pi * Ar;
            }
        }
    }
    {   // q5: expand comps (amp bit0), building whole v2f
        const float4 mq = M[5];
        GCOEF(mq, C[5], S[5], g00r, g00i, g01r, g01i)
        const v2f KA1 = (v2f){g00r, -g01r};   // (A_r, B_r)
        const v2f KA2 = (v2f){g00i,  g01i};   // (A_i, B_i)
#pragma unroll
        for (int m = 0; m < 32; m++) {
            const float pr = ar0[m], pi = ai0[m];
            Rr[m] = pr * KA1 - pi * KA2;
            Ri[m] = pr * KA2 + pi * KA1;
        }
    }

    // ---- layers 1,2: ring-conjugated gates (zero ring instructions) ----
    APPLY_GATE(1, 0);
    APPLY_GATE(1, 1);
    APPLY_GATE(1, 2);
    APPLY_GATE(1, 3);
    APPLY_GATE(1, 4);
    APPLY_GATE(1, 5);
    APPLY_GATE(2, 0);
    APPLY_GATE(2, 1);
    APPLY_GATE(2, 2);
    APPLY_GATE(2, 3);
    APPLY_GATE(2, 4);
    APPLY_GATE(2, 5);

    // ---- expvals: 3rd ring folded into sign masks SIGMA(3,q) ----
    v2f A0 = (v2f)(0.f), A1 = (v2f)(0.f), A2 = (v2f)(0.f),
        A3 = (v2f)(0.f), A4 = (v2f)(0.f), A5 = (v2f)(0.f);
#pragma unroll
    for (int m = 0; m < 32; m++) {
        const v2f p2 = Rr[m] * Rr[m] + Ri[m] * Ri[m];
        A0 += (__builtin_popcount((SIGMA(3,0) >> 1) & m) & 1) ? -p2 : p2;
        A1 += (__builtin_popcount((SIGMA(3,1) >> 1) & m) & 1) ? -p2 : p2;
        A2 += (__builtin_popcount((SIGMA(3,2) >> 1) & m) & 1) ? -p2 : p2;
        A3 += (__builtin_popcount((SIGMA(3,3) >> 1) & m) & 1) ? -p2 : p2;
        A4 += (__builtin_popcount((SIGMA(3,4) >> 1) & m) & 1) ? -p2 : p2;
        A5 += (__builtin_popcount((SIGMA(3,5) >> 1) & m) & 1) ? -p2 : p2;
    }
    const float F0 = (SIGMA(3,0) & 1) ? (A0.x - A0.y) : (A0.x + A0.y);
    const float F1 = (SIGMA(3,1) & 1) ? (A1.x - A1.y) : (A1.x + A1.y);
    const float F2 = (SIGMA(3,2) & 1) ? (A2.x - A2.y) : (A2.x + A2.y);
    const float F3 = (SIGMA(3,3) & 1) ? (A3.x - A3.y) : (A3.x + A3.y);
    const float F4 = (SIGMA(3,4) & 1) ? (A4.x - A4.y) : (A4.x + A4.y);
    const float F5 = (SIGMA(3,5) & 1) ? (A5.x - A5.y) : (A5.x + A5.y);

    float2* o2 = (float2*)out;
    o2[b * 3 + 0] = make_float2(F0, F1);
    o2[b * 3 + 1] = make_float2(F2, F3);
    o2[b * 3 + 2] = make_float2(F4, F5);
}

extern "C" void kernel_launch(void* const* d_in, const int* in_sizes, int n_in,
                              void* d_out, int out_size, void* d_ws, size_t ws_size,
                              hipStream_t stream) {
    const float* x = (const float*)d_in[0];
    const float* w = (const float*)d_in[1];
    float* out = (float*)d_out;
    float4* M = (float4*)d_ws;  // 18 * 16 B
    const int B = in_sizes[0] / NQ;
    gate_prep<<<1, 64, 0, stream>>>(w, M);
    const int block = 256;
    const int grid = (B + block - 1) / block;
    qsim_kernel<<<grid, block, 0, stream>>>(x, M, out, B);
}

// Round 17
// 91.936 us; speedup vs baseline: 1.9492x; 1.9492x over previous
//
#include <hip/hip_runtime.h>
#include <math.h>

#define NQ 6
#define NL 3

typedef float v2f __attribute__((ext_vector_type(2)));

// ---------- CNOT-ring permutation (bench-validated rounds 2-16) ----------
constexpr int cnot_map(int k, int ctrl, int tgt) {
    const int cb = 1 << (5 - ctrl), tb = 1 << (5 - tgt);
    return (k & cb) ? (k ^ tb) : k;
}
constexpr int ring_map(int k) {
    k = cnot_map(k, 5, 0);
    k = cnot_map(k, 4, 5);
    k = cnot_map(k, 3, 4);
    k = cnot_map(k, 2, 3);
    k = cnot_map(k, 1, 2);
    k = cnot_map(k, 0, 1);
    return k;
}
constexpr int ringN(int k, int n) {
    for (int i = 0; i < n; i++) k = ring_map(k);
    return k;
}
constexpr int inv_ringN(int p, int n) {
    for (int k = 0; k < 64; k++) if (ringN(k, n) == p) return k;
    return -1;
}
// Gate on logical qubit q with l rings skipped: physical pair mask Δ
constexpr int DELTA(int l, int q) { return ringN(1 << (5 - q), l); }
// Side mask σ: parity(σ & p) == logical bit (5-q) of physical p
constexpr int SIGMA(int l, int q) {
    int m = 0;
    for (int i = 0; i < 6; i++)
        if ((inv_ringN(1 << i, l) >> (5 - q)) & 1) m |= 1 << i;
    return m;
}
// Exhaustive verification vs validated ring_map: pairing linearity, side
// indicator for every physical index, and σ·Δ = 1 (pair straddles the gate).
constexpr bool check_conj() {
    int fwd[4][64] = {}, inv[4][64] = {};
    for (int k = 0; k < 64; k++) fwd[0][k] = k;
    for (int l = 1; l <= 3; l++)
        for (int k = 0; k < 64; k++) fwd[l][k] = ring_map(fwd[l - 1][k]);
    for (int l = 0; l <= 3; l++)
        for (int k = 0; k < 64; k++) inv[l][fwd[l][k]] = k;
    for (int l = 0; l <= 3; l++)
        for (int q = 0; q < 6; q++) {
            const int sg = SIGMA(l, q), dl = DELTA(l, q);
            for (int p = 0; p < 64; p++)
                if ((__builtin_popcount(sg & p) & 1) != ((inv[l][p] >> (5 - q)) & 1))
                    return false;
            if ((__builtin_popcount(sg & dl) & 1) != 1) return false;
            for (int k = 0; k < 64; k++)
                if (fwd[l][k ^ (1 << (5 - q))] != (fwd[l][k] ^ dl)) return false;
        }
    return true;
}
static_assert(check_conj(), "ring-conjugation masks mismatch vs validated ring_map");

// ---- prep kernel: M = RZ(a2)@RY(a1)@RZ(a0), SU(2) form (m00, m01) ----
__global__ void gate_prep(const float* __restrict__ w, float4* __restrict__ M) {
    const int g = threadIdx.x;
    if (g >= NL * NQ) return;
    const float a0 = w[g * 3 + 0], a1 = w[g * 3 + 1], a2 = w[g * 3 + 2];
    const float ch = cosf(0.5f * a1), sh = sinf(0.5f * a1);
    const float cp = cosf(0.5f * (a0 + a2)), sp = sinf(0.5f * (a0 + a2));
    const float cm = cosf(0.5f * (a0 - a2)), sm = sinf(0.5f * (a0 - a2));
    M[g] = make_float4(ch * cp, -ch * sp, -sh * cm, -sh * sm);
}

// G = M @ RY(c,s): g00 = m00*c + m01*s ; g01 = -m00*s + m01*c  (SU(2))
#define GCOEF(mq, c, s, g00r, g00i, g01r, g01i)                         \
    const float g00r = (mq).x * (c) + (mq).z * (s);                     \
    const float g00i = (mq).y * (c) + (mq).w * (s);                     \
    const float g01r = (mq).z * (c) - (mq).x * (s);                     \
    const float g01i = (mq).w * (c) - (mq).y * (s);

// Element coefficients by side s: A_0=g00, A_1=conj g00 (same real part);
// B_0=g01, B_1=-conj g01 (same imag part). Per-element:
//   new_r = e_r*g00r - e_i*KAi + p_r*KBr - p_i*g01i
//   new_i = e_i*g00r + e_r*KAi + p_i*KBr + p_r*g01i
// KAi(side) = side ? -g00i : g00i ; KBr(side) = side ? -g01r : g01r.
// Layout: physical index p = 2m + c (vector m = bits5..1, comp c = bit0).
// Pairing: m <-> m ^ vm; canonical selector = one bit of vm (round-14 fix).
#define APPLY_GATE(L, Q) do {                                               \
    constexpr int dlt = DELTA(L, Q);                                        \
    constexpr int sgm = SIGMA(L, Q);                                        \
    constexpr int vm  = dlt >> 1;                                           \
    constexpr int cf  = dlt & 1;                                            \
    constexpr int tt  = sgm & 1;                                            \
    constexpr int cvm = vm & (-vm);   /* single canonical bit of vm */      \
    const float4 mq = M[(L) * NQ + (Q)];                                    \
    GCOEF(mq, C[Q], S[Q], g00r, g00i, g01r, g01i)                           \
    if constexpr (cf == 0) {                                                \
        /* partner keeps comp */                                            \
        _Pragma("unroll")                                                   \
        for (int m = 0; m < 32; m++) if (!(m & cvm)) {                      \
            const int m2 = m ^ vm;                                          \
            const int s0 = __builtin_popcount(sgm & (2 * m)) & 1;           \
            const v2f KAi = (v2f){ s0 ? -g00i : g00i, (s0^tt) ? -g00i : g00i }; \
            const v2f KBr = (v2f){ s0 ? -g01r : g01r, (s0^tt) ? -g01r : g01r }; \
            const v2f R0 = Rr[m], I0 = Ri[m], R1 = Rr[m2], I1 = Ri[m2];     \
            Rr[m]  = R0 * g00r - I0 * KAi + R1 * KBr - I1 * g01i;           \
            Ri[m]  = I0 * g00r + R0 * KAi + I1 * KBr + R1 * g01i;           \
            Rr[m2] = R1 * g00r + I1 * KAi - R0 * KBr - I0 * g01i;           \
            Ri[m2] = I1 * g00r - R1 * KAi - I0 * KBr + R0 * g01i;           \
        }                                                                   \
    } else if constexpr (vm == 0) {                                         \
        /* pure comp-flip: partner = own .yx */                             \
        _Pragma("unroll")                                                   \
        for (int m = 0; m < 32; m++) {                                      \
            const int s0 = __builtin_popcount(sgm & (2 * m)) & 1;           \
            const v2f KAi = (v2f){ s0 ? -g00i : g00i, (s0^tt) ? -g00i : g00i }; \
            const v2f KBr = (v2f){ s0 ? -g01r : g01r, (s0^tt) ? -g01r : g01r }; \
            const v2f R0 = Rr[m], I0 = Ri[m];                               \
            const v2f R0s = (v2f){R0.y, R0.x}, I0s = (v2f){I0.y, I0.x};     \
            Rr[m] = R0 * g00r - I0 * KAi + R0s * KBr - I0s * g01i;          \
            Ri[m] = I0 * g00r + R0 * KAi + I0s * KBr + R0s * g01i;          \
        }                                                                   \
    } else {                                                                \
        /* cross-vector + comp-flip: partner = other vector .yx */          \
        _Pragma("unroll")                                                   \
        for (int m = 0; m < 32; m++) if (!(m & cvm)) {                      \
            const int m2 = m ^ vm;                                          \
            const int s0 = __builtin_popcount(sgm & (2 * m)) & 1;           \
            const v2f KAi  = (v2f){ s0 ? -g00i : g00i, (s0^tt) ? -g00i : g00i };    \
            const v2f KBr  = (v2f){ s0 ? -g01r : g01r, (s0^tt) ? -g01r : g01r };    \
            const v2f KAi2 = (v2f){ (s0^1^tt) ? -g00i : g00i, (s0^1) ? -g00i : g00i }; \
            const v2f KBr2 = (v2f){ (s0^1^tt) ? -g01r : g01r, (s0^1) ? -g01r : g01r }; \
            const v2f R0 = Rr[m], I0 = Ri[m], R1 = Rr[m2], I1 = Ri[m2];     \
            const v2f R1s = (v2f){R1.y, R1.x}, I1s = (v2f){I1.y, I1.x};     \
            const v2f R0s = (v2f){R0.y, R0.x}, I0s = (v2f){I0.y, I0.x};     \
            Rr[m]  = R0 * g00r - I0 * KAi  + R1s * KBr  - I1s * g01i;       \
            Ri[m]  = I0 * g00r + R0 * KAi  + I1s * KBr  + R1s * g01i;       \
            Rr[m2] = R1 * g00r - I1 * KAi2 + R0s * KBr2 - I0s * g01i;       \
            Ri[m2] = I1 * g00r + R1 * KAi2 + I0s * KBr2 + R0s * g01i;       \
        }                                                                   \
    }                                                                       \
} while (0)

// Launch-bounds empirical mapping on this toolchain (rounds 2/3/15/16):
// (256,1)->256 VGPR cap, (256,2)->128, (256,4)->64 (catastrophic spill).
// Default chose 104 < 128-float live state => AGPR shuffle fat. (256,1)
// gives the allocator room for the full ~154-float live set; co-residency
// drops 4->3 waves/SIMD, acceptable since we're issue-bound (rounds 9/10).
__global__ __launch_bounds__(256, 1)
void qsim_kernel(const float* __restrict__ x, const float4* __restrict__ M,
                 float* __restrict__ out, int B) {
    const int b = blockIdx.x * blockDim.x + threadIdx.x;
    if (b >= B) return;

    const float2* x2 = (const float2*)x;
    const float2 v0 = x2[b * 3 + 0];
    const float2 v1 = x2[b * 3 + 1];
    const float2 v2 = x2[b * 3 + 2];
    const float xi[NQ] = {v0.x, v0.y, v1.x, v1.y, v2.x, v2.y};

    // phi = (pi/2)*tanh(x); v_sin/v_cos take REVOLUTIONS: |t/4| <= 0.25
    float C[NQ], S[NQ];
#pragma unroll
    for (int i = 0; i < NQ; i++) {
        const float e = __builtin_amdgcn_exp2f(2.885390081777927f * xi[i]); // e^{2x}
        const float t = 1.0f - 2.0f * __builtin_amdgcn_rcpf(e + 1.0f);      // tanh(x)
        S[i] = __builtin_amdgcn_sinf(0.25f * t);
        C[i] = __builtin_amdgcn_cosf(0.25f * t);
    }

    // Full 64-amp state per thread, packed: Rr[m]/Ri[m] comps = amps 2m, 2m+1
    v2f Rr[32], Ri[32];

    // ---- layer 0 on |0>: product-state cascade, scalar until q5 ----
    float ar0[32], ai0[32];
    {
        const float4 m0 = M[0];
        GCOEF(m0, C[0], S[0], g00r, g00i, g01r, g01i)
        ar0[0]  = g00r;  ai0[0]  = g00i;    // amp 0  (m=0)
        ar0[16] = -g01r; ai0[16] = g01i;    // amp 32 (m=16): -conj(g01)
    }
#pragma unroll
    for (int q = 1; q < 5; q++) {
        const float4 mq = M[q];
        GCOEF(mq, C[q], S[q], g00r, g00i, g01r, g01i)
        const float Ar = g00r, Ai = g00i;     // bit=0 factor
        const float Br = -g01r, Bi = g01i;    // bit=1 factor (-conj g01)
        const int mb = 16 >> q;
#pragma unroll
        for (int m = 0; m < 32; m++) {
            if ((m & ((32 >> q) - 1)) == 0) {  // occupied set
                const float pr = ar0[m], pi = ai0[m];
                ar0[m | mb] = pr * Br - pi * Bi;
                ai0[m | mb] = pr * Bi + pi * Br;
                ar0[m] = pr * Ar - pi * Ai;
                ai0[m] = pr * Ai + pi * Ar;
            }
        }
    }
    {   // q5: expand comps (amp bit0), building whole v2f
        const float4 mq = M[5];
        GCOEF(mq, C[5], S[5], g00r, g00i, g01r, g01i)
        const v2f KA1 = (v2f){g00r, -g01r};   // (A_r, B_r)
        const v2f KA2 = (v2f){g00i,  g01i};   // (A_i, B_i)
#pragma unroll
        for (int m = 0; m < 32; m++) {
            const float pr = ar0[m], pi = ai0[m];
            Rr[m] = pr * KA1 - pi * KA2;
            Ri[m] = pr * KA2 + pi * KA1;
        }
    }

    // ---- layers 1,2: ring-conjugated gates (zero ring instructions) ----
    APPLY_GATE(1, 0);
    APPLY_GATE(1, 1);
    APPLY_GATE(1, 2);
    APPLY_GATE(1, 3);
    APPLY_GATE(1, 4);
    APPLY_GATE(1, 5);
    APPLY_GATE(2, 0);
    APPLY_GATE(2, 1);
    APPLY_GATE(2, 2);
    APPLY_GATE(2, 3);
    APPLY_GATE(2, 4);
    APPLY_GATE(2, 5);

    // ---- expvals: 3rd ring folded into sign masks SIGMA(3,q) ----
    v2f A0 = (v2f)(0.f), A1 = (v2f)(0.f), A2 = (v2f)(0.f),
        A3 = (v2f)(0.f), A4 = (v2f)(0.f), A5 = (v2f)(0.f);
#pragma unroll
    for (int m = 0; m < 32; m++) {
        const v2f p2 = Rr[m] * Rr[m] + Ri[m] * Ri[m];
        A0 += (__builtin_popcount((SIGMA(3,0) >> 1) & m) & 1) ? -p2 : p2;
        A1 += (__builtin_popcount((SIGMA(3,1) >> 1) & m) & 1) ? -p2 : p2;
        A2 += (__builtin_popcount((SIGMA(3,2) >> 1) & m) & 1) ? -p2 : p2;
        A3 += (__builtin_popcount((SIGMA(3,3) >> 1) & m) & 1) ? -p2 : p2;
        A4 += (__builtin_popcount((SIGMA(3,4) >> 1) & m) & 1) ? -p2 : p2;
        A5 += (__builtin_popcount((SIGMA(3,5) >> 1) & m) & 1) ? -p2 : p2;
    }
    const float F0 = (SIGMA(3,0) & 1) ? (A0.x - A0.y) : (A0.x + A0.y);
    const float F1 = (SIGMA(3,1) & 1) ? (A1.x - A1.y) : (A1.x + A1.y);
    const float F2 = (SIGMA(3,2) & 1) ? (A2.x - A2.y) : (A2.x + A2.y);
    const float F3 = (SIGMA(3,3) & 1) ? (A3.x - A3.y) : (A3.x + A3.y);
    const float F4 = (SIGMA(3,4) & 1) ? (A4.x - A4.y) : (A4.x + A4.y);
    const float F5 = (SIGMA(3,5) & 1) ? (A5.x - A5.y) : (A5.x + A5.y);

    float2* o2 = (float2*)out;
    o2[b * 3 + 0] = make_float2(F0, F1);
    o2[b * 3 + 1] = make_float2(F2, F3);
    o2[b * 3 + 2] = make_float2(F4, F5);
}

extern "C" void kernel_launch(void* const* d_in, const int* in_sizes, int n_in,
                              void* d_out, int out_size, void* d_ws, size_t ws_size,
                              hipStream_t stream) {
    const float* x = (const float*)d_in[0];
    const float* w = (const float*)d_in[1];
    float* out = (float*)d_out;
    float4* M = (float4*)d_ws;  // 18 * 16 B
    const int B = in_sizes[0] / NQ;
    gate_prep<<<1, 64, 0, stream>>>(w, M);
    const int block = 256;
    const int grid = (B + block - 1) / block;
    qsim_kernel<<<grid, block, 0, stream>>>(x, M, out, B);
}